// Round 4
// baseline (323.394 us; speedup 1.0000x reference)
//
#include <hip/hip_runtime.h>

#define NN 100000
#define EE 640000
#define DD 128
#define NB 391   // ceil(NN/256)

// k_setup block ranges
#define CVT_BLKS  12500   // 12500*256*4 = 12,800,000 = NN*DD exactly
#define PREP_BLKS 128     // 2*128*128 / 256
#define ZERO_BLKS 98      // ceil(25000 int4 / 256)

typedef short bf16x8 __attribute__((ext_vector_type(8)));
typedef float f32x4 __attribute__((ext_vector_type(4)));

__device__ __forceinline__ unsigned short f2bf(float f) {
    union { float f; unsigned int u; } a; a.f = f;
    unsigned int u = a.u + 0x7fffu + ((a.u >> 16) & 1u);   // RNE
    return (unsigned short)(u >> 16);
}

__device__ __forceinline__ int wave_incl_scan(int v, int lane) {
#pragma unroll
    for (int d = 1; d < 64; d <<= 1) {
        int u = __shfl_up(v, d, 64);
        if (lane >= d) v += u;
    }
    return v;
}

// ------------- setup: x->bf16, W->bf16 transposed, deg=0 (one kernel) ----------
__global__ __launch_bounds__(256) void k_setup(const float* __restrict__ x,
                                               const float* __restrict__ W1,
                                               const float* __restrict__ W2,
                                               unsigned short* __restrict__ xb,
                                               unsigned short* __restrict__ w1t,
                                               unsigned short* __restrict__ w2t,
                                               int* __restrict__ deg) {
    int b = blockIdx.x, t = threadIdx.x;
    if (b < CVT_BLKS) {
        int i = (b * 256 + t) * 4;
        float4 v = *reinterpret_cast<const float4*>(x + i);
        unsigned int u0 = (unsigned)f2bf(v.x) | ((unsigned)f2bf(v.y) << 16);
        unsigned int u1 = (unsigned)f2bf(v.z) | ((unsigned)f2bf(v.w) << 16);
        *reinterpret_cast<uint2*>(xb + i) = make_uint2(u0, u1);
    } else if (b < CVT_BLKS + PREP_BLKS) {
        int idx = (b - CVT_BLKS) * 256 + t;            // 0 .. 32767
        const float* W = (idx < DD * DD) ? W1 : W2;
        unsigned short* O = (idx < DD * DD) ? w1t : w2t;
        int i = idx & (DD * DD - 1);
        int n = i >> 7, k = i & (DD - 1);
        O[i] = f2bf(W[k * DD + n]);                    // O[n*128+k] = W[k][n]
    } else {
        int idx = (b - CVT_BLKS - PREP_BLKS) * 256 + t;
        if (idx < 25000)
            reinterpret_cast<int4*>(deg)[idx] = make_int4(0, 0, 0, 0);
    }
}

// ---------------- CSR build ----------------------------------------------------
__global__ __launch_bounds__(256) void k_hist(const int* __restrict__ ei,
                                              int* __restrict__ deg) {
    int e = blockIdx.x * 256 + threadIdx.x;
    if (e >= EE) return;
    atomicAdd(&deg[ei[EE + e]], 1);
}

__global__ __launch_bounds__(256) void k_scan1(const int* __restrict__ deg,
                                               int* __restrict__ bsum) {
    int i = blockIdx.x * 256 + threadIdx.x;
    int v = (i < NN) ? deg[i] : 0;
#pragma unroll
    for (int d = 32; d; d >>= 1) v += __shfl_down(v, d, 64);
    __shared__ int wsum[4];
    if ((threadIdx.x & 63) == 0) wsum[threadIdx.x >> 6] = v;
    __syncthreads();
    if (threadIdx.x == 0) bsum[blockIdx.x] = wsum[0] + wsum[1] + wsum[2] + wsum[3];
}

__global__ __launch_bounds__(512) void k_scan2(int* __restrict__ bsum,
                                               int* __restrict__ offs) {
    int t = threadIdx.x, lane = t & 63, w = t >> 6;
    int v = (t < NB) ? bsum[t] : 0;
    int s = wave_incl_scan(v, lane);
    __shared__ int wsum[8];
    if (lane == 63) wsum[w] = s;
    __syncthreads();
    int off = 0;
    for (int k = 0; k < w; ++k) off += wsum[k];
    if (t < NB) bsum[t] = off + s - v;   // exclusive block offsets
    if (t == 0) offs[NN] = EE;
}

__global__ __launch_bounds__(256) void k_scan3(const int* __restrict__ deg,
                                               const int* __restrict__ bsum,
                                               int* __restrict__ offs) {
    int t = threadIdx.x, lane = t & 63, w = t >> 6;
    int i = blockIdx.x * 256 + t;
    int v = (i < NN) ? deg[i] : 0;
    int s = wave_incl_scan(v, lane);
    __shared__ int wsum[4];
    if (lane == 63) wsum[w] = s;
    __syncthreads();
    int off = bsum[blockIdx.x];
    for (int k = 0; k < w; ++k) off += wsum[k];
    if (i < NN) offs[i] = off + s - v;   // exclusive
}

__global__ __launch_bounds__(256) void k_fill(const int* __restrict__ ei,
                                              int* __restrict__ deg,
                                              const int* __restrict__ offs,
                                              int* __restrict__ bucket) {
    int e = blockIdx.x * 256 + threadIdx.x;
    if (e >= EE) return;
    int r = ei[e];
    int c = ei[EE + e];
    int p = atomicSub(&deg[c], 1) - 1;   // deg reused as cursor; order irrelevant
    bucket[offs[c] + p] = r;
}

// ------- fused: per 128-row block, wave-gather h0 into LDS (bf16), then MLP ----
__global__ __launch_bounds__(256, 2) void k_fused(const unsigned short* __restrict__ xb,
                                                  const int* __restrict__ offs,
                                                  const int* __restrict__ bucket,
                                                  const unsigned short* __restrict__ w1t,
                                                  const unsigned short* __restrict__ w2t,
                                                  const float* __restrict__ b1,
                                                  const float* __restrict__ b2,
                                                  float* __restrict__ out) {
    __shared__ unsigned short lds[DD * DD];  // 32 KB, swizzled h tile
    const int t  = threadIdx.x;
    const int w  = t >> 6, l = t & 63;
    const int wr = w >> 1, wc = w & 1;
    const int hi = l >> 4, lo = l & 15;
    const long base_row = (long)blockIdx.x * 128;
    const unsigned int* xr = reinterpret_cast<const unsigned int*>(xb);  // row n: xr[n*64+l]

    // ---- phase 0: gather. wave w handles local rows w*32 .. w*32+31 ----
    for (int i = 0; i < 32; ++i) {
        int r = w * 32 + i;
        long n = base_row + r;
        float ax = 0.f, ay = 0.f;
        if (n < NN) {
            unsigned int u = xr[(size_t)n * 64 + l];   // self term
            ax = __uint_as_float(u << 16);
            ay = __uint_as_float(u & 0xffff0000u);
            int j = offs[n], je = offs[n + 1];
            for (; j + 3 < je; j += 4) {
                int a0 = bucket[j], a1 = bucket[j + 1], a2 = bucket[j + 2], a3 = bucket[j + 3];
                unsigned int u0 = xr[(size_t)a0 * 64 + l];
                unsigned int u1 = xr[(size_t)a1 * 64 + l];
                unsigned int u2 = xr[(size_t)a2 * 64 + l];
                unsigned int u3 = xr[(size_t)a3 * 64 + l];
                ax += __uint_as_float(u0 << 16) + __uint_as_float(u1 << 16)
                    + __uint_as_float(u2 << 16) + __uint_as_float(u3 << 16);
                ay += __uint_as_float(u0 & 0xffff0000u) + __uint_as_float(u1 & 0xffff0000u)
                    + __uint_as_float(u2 & 0xffff0000u) + __uint_as_float(u3 & 0xffff0000u);
            }
            for (; j < je; ++j) {
                unsigned int u = xr[(size_t)bucket[j] * 64 + l];
                ax += __uint_as_float(u << 16);
                ay += __uint_as_float(u & 0xffff0000u);
            }
        }
        unsigned int p = (unsigned)f2bf(ax) | ((unsigned)f2bf(ay) << 16);
        int byte = (r * 256 + l * 4) ^ ((r & 7) << 4);   // col = 2l
        *reinterpret_cast<unsigned int*>(reinterpret_cast<char*>(lds) + byte) = p;
    }
    __syncthreads();

    const f32x4 zero = {0.f, 0.f, 0.f, 0.f};

    // ---- GEMM1 ----
    bf16x8 bw1[4][4];
#pragma unroll
    for (int n = 0; n < 4; ++n)
#pragma unroll
        for (int k = 0; k < 4; ++k)
            bw1[n][k] = *reinterpret_cast<const bf16x8*>(
                w1t + (wc * 64 + n * 16 + lo) * DD + k * 32 + hi * 8);

    f32x4 acc[4][4];
#pragma unroll
    for (int m = 0; m < 4; ++m)
#pragma unroll
        for (int n = 0; n < 4; ++n) acc[m][n] = zero;
#pragma unroll
    for (int m = 0; m < 4; ++m) {
        bf16x8 a[4];
        int r = wr * 64 + m * 16 + lo;
#pragma unroll
        for (int k = 0; k < 4; ++k) {
            int byte = (r * 256 + k * 64 + hi * 16) ^ ((r & 7) << 4);
            a[k] = *reinterpret_cast<const bf16x8*>(reinterpret_cast<const char*>(lds) + byte);
        }
#pragma unroll
        for (int n = 0; n < 4; ++n)
#pragma unroll
            for (int k = 0; k < 4; ++k)
                acc[m][n] = __builtin_amdgcn_mfma_f32_16x16x32_bf16(a[k], bw1[n][k], acc[m][n], 0, 0, 0);
    }
    __syncthreads();

    // ---- epilogue 1: h1 = relu(acc+b1) -> LDS (swizzled) ----
    float bias1[4];
#pragma unroll
    for (int n = 0; n < 4; ++n) bias1[n] = b1[wc * 64 + n * 16 + lo];
#pragma unroll
    for (int m = 0; m < 4; ++m)
#pragma unroll
        for (int n = 0; n < 4; ++n)
#pragma unroll
            for (int g = 0; g < 4; ++g) {
                int row = wr * 64 + m * 16 + hi * 4 + g;   // D: col=lane&15, row=(lane>>4)*4+reg
                int col = wc * 64 + n * 16 + lo;
                float v = fmaxf(acc[m][n][g] + bias1[n], 0.f);
                int byte = (row * 256 + col * 2) ^ ((row & 7) << 4);
                *reinterpret_cast<unsigned short*>(reinterpret_cast<char*>(lds) + byte) = f2bf(v);
            }
    __syncthreads();

    // ---- GEMM2 ----
    bf16x8 bw2[4][4];
#pragma unroll
    for (int n = 0; n < 4; ++n)
#pragma unroll
        for (int k = 0; k < 4; ++k)
            bw2[n][k] = *reinterpret_cast<const bf16x8*>(
                w2t + (wc * 64 + n * 16 + lo) * DD + k * 32 + hi * 8);

    f32x4 acc2[4][4];
#pragma unroll
    for (int m = 0; m < 4; ++m)
#pragma unroll
        for (int n = 0; n < 4; ++n) acc2[m][n] = zero;
#pragma unroll
    for (int m = 0; m < 4; ++m) {
        bf16x8 a[4];
        int r = wr * 64 + m * 16 + lo;
#pragma unroll
        for (int k = 0; k < 4; ++k) {
            int byte = (r * 256 + k * 64 + hi * 16) ^ ((r & 7) << 4);
            a[k] = *reinterpret_cast<const bf16x8*>(reinterpret_cast<const char*>(lds) + byte);
        }
#pragma unroll
        for (int n = 0; n < 4; ++n)
#pragma unroll
            for (int k = 0; k < 4; ++k)
                acc2[m][n] = __builtin_amdgcn_mfma_f32_16x16x32_bf16(a[k], bw2[n][k], acc2[m][n], 0, 0, 0);
    }

    // ---- store out = acc2 + b2 (f32) ----
    float bias2[4];
#pragma unroll
    for (int n = 0; n < 4; ++n) bias2[n] = b2[wc * 64 + n * 16 + lo];
#pragma unroll
    for (int m = 0; m < 4; ++m)
#pragma unroll
        for (int n = 0; n < 4; ++n)
#pragma unroll
            for (int g = 0; g < 4; ++g) {
                long row = base_row + wr * 64 + m * 16 + hi * 4 + g;
                if (row < NN)
                    out[row * DD + wc * 64 + n * 16 + lo] = acc2[m][n][g] + bias2[n];
            }
}

extern "C" void kernel_launch(void* const* d_in, const int* in_sizes, int n_in,
                              void* d_out, int out_size, void* d_ws, size_t ws_size,
                              hipStream_t stream) {
    const float* x  = (const float*)d_in[0];
    const int*   ei = (const int*)d_in[1];
    const float* W1 = (const float*)d_in[2];
    const float* b1 = (const float*)d_in[3];
    const float* W2 = (const float*)d_in[4];
    const float* b2 = (const float*)d_in[5];
    float* out = (float*)d_out;

    char* ws = (char*)d_ws;
    unsigned short* xb  = (unsigned short*)ws;                 // 25,600,000 B
    unsigned short* w1t = (unsigned short*)(ws + 25600000);    // 32 KB
    unsigned short* w2t = w1t + DD * DD;                       // 32 KB
    int* deg    = (int*)(ws + 25600000 + 65536);               // NN ints
    int* offs   = deg + NN;                                    // NN+1 ints
    int* bsum   = offs + NN + 1;                               // NB ints (pad 512)
    int* bucket = bsum + 512;                                  // EE ints

    k_setup<<<CVT_BLKS + PREP_BLKS + ZERO_BLKS, 256, 0, stream>>>(x, W1, W2, xb, w1t, w2t, deg);
    k_hist<<<(EE + 255) / 256, 256, 0, stream>>>(ei, deg);
    k_scan1<<<NB, 256, 0, stream>>>(deg, bsum);
    k_scan2<<<1, 512, 0, stream>>>(bsum, offs);
    k_scan3<<<NB, 256, 0, stream>>>(deg, bsum, offs);
    k_fill<<<(EE + 255) / 256, 256, 0, stream>>>(ei, deg, offs, bucket);
    k_fused<<<(NN + 127) / 128, 256, 0, stream>>>(xb, offs, bucket, w1t, w2t, b1, b2, out);
}

// Round 6
// 313.366 us; speedup vs baseline: 1.0320x; 1.0320x over previous
//
#include <hip/hip_runtime.h>

#define NN 100000
#define EE 640000
#define DD 128

// k_setup block ranges
#define CVT_BLKS  12500   // 12500*256*4 = 12,800,000 = NN*DD exactly
#define PREP_BLKS 128     // 2*128*128 / 256
#define ZERO_BLKS 98      // ceil(25000 int4 / 256)

typedef short bf16x8 __attribute__((ext_vector_type(8)));
typedef float f32x4 __attribute__((ext_vector_type(4)));

__device__ __forceinline__ unsigned short f2bf(float f) {
    union { float f; unsigned int u; } a; a.f = f;
    unsigned int u = a.u + 0x7fffu + ((a.u >> 16) & 1u);   // RNE
    return (unsigned short)(u >> 16);
}

__device__ __forceinline__ int wave_incl_scan(int v, int lane) {
#pragma unroll
    for (int d = 1; d < 64; d <<= 1) {
        int u = __shfl_up(v, d, 64);
        if (lane >= d) v += u;
    }
    return v;
}

// ------------- setup: x->bf16, W->bf16 transposed, deg=0 (one kernel) ----------
__global__ __launch_bounds__(256) void k_setup(const float* __restrict__ x,
                                               const float* __restrict__ W1,
                                               const float* __restrict__ W2,
                                               unsigned short* __restrict__ xb,
                                               unsigned short* __restrict__ w1t,
                                               unsigned short* __restrict__ w2t,
                                               int* __restrict__ deg) {
    int b = blockIdx.x, t = threadIdx.x;
    if (b < CVT_BLKS) {
        int i = (b * 256 + t) * 4;
        float4 v = *reinterpret_cast<const float4*>(x + i);
        unsigned int u0 = (unsigned)f2bf(v.x) | ((unsigned)f2bf(v.y) << 16);
        unsigned int u1 = (unsigned)f2bf(v.z) | ((unsigned)f2bf(v.w) << 16);
        *reinterpret_cast<uint2*>(xb + i) = make_uint2(u0, u1);
    } else if (b < CVT_BLKS + PREP_BLKS) {
        int idx = (b - CVT_BLKS) * 256 + t;            // 0 .. 32767
        const float* W = (idx < DD * DD) ? W1 : W2;
        unsigned short* O = (idx < DD * DD) ? w1t : w2t;
        int i = idx & (DD * DD - 1);
        int n = i >> 7, k = i & (DD - 1);
        O[i] = f2bf(W[k * DD + n]);                    // O[n*128+k] = W[k][n]
    } else {
        int idx = (b - CVT_BLKS - PREP_BLKS) * 256 + t;
        if (idx < 25000)
            reinterpret_cast<int4*>(deg)[idx] = make_int4(0, 0, 0, 0);
    }
}

// ---------------- CSR build ----------------------------------------------------
__global__ __launch_bounds__(256) void k_hist(const int* __restrict__ ei,
                                              int* __restrict__ deg) {
    int e = blockIdx.x * 256 + threadIdx.x;
    if (e >= EE) return;
    atomicAdd(&deg[ei[EE + e]], 1);
}

// single-block exclusive scan over deg[0..NN) -> offs; offs[NN]=EE.
// 16 waves; wave w owns contiguous chunk of 6272 elems, scanned in 98
// coalesced 64-wide shfl-scan steps.
__global__ __launch_bounds__(1024) void k_scan(const int* __restrict__ deg,
                                               int* __restrict__ offs) {
    int t = threadIdx.x, lane = t & 63, w = t >> 6;
    const int CHUNK = 6272;                       // 16*6272 = 100352 >= NN
    int base = w * CHUNK;
    int sum = 0;
    for (int k = 0; k < CHUNK; k += 64) {
        int i = base + k + lane;
        if (i < NN) sum += deg[i];
    }
    int s = wave_incl_scan(sum, lane);            // lane63 = wave total
    __shared__ int wsum[16];
    if (lane == 63) wsum[w] = s;
    __syncthreads();
    int run = 0;
    for (int k = 0; k < w; ++k) run += wsum[k];   // exclusive wave offset
    for (int k = 0; k < CHUNK; k += 64) {
        int i = base + k + lane;
        int v = (i < NN) ? deg[i] : 0;
        int sc = wave_incl_scan(v, lane);
        if (i < NN) offs[i] = run + sc - v;       // exclusive
        run += __shfl(sc, 63, 64);
    }
    if (t == 0) offs[NN] = EE;
}

__global__ __launch_bounds__(256) void k_fill(const int* __restrict__ ei,
                                              int* __restrict__ deg,
                                              const int* __restrict__ offs,
                                              int* __restrict__ bucket) {
    int e = blockIdx.x * 256 + threadIdx.x;
    if (e >= EE) return;
    int r = ei[e];
    int c = ei[EE + e];
    int p = atomicSub(&deg[c], 1) - 1;   // deg reused as cursor; order irrelevant
    bucket[offs[c] + p] = r;
}

// -------- gather: hb[n] = bf16( x[n] + sum_{src->n} x[src] ), one node/wave ----
__global__ __launch_bounds__(256) void k_gather(const unsigned int* __restrict__ xr,
                                                const int* __restrict__ offs,
                                                const int* __restrict__ bucket,
                                                unsigned int* __restrict__ hb) {
    int gid = blockIdx.x * 256 + threadIdx.x;
    int n = gid >> 6;
    if (n >= NN) return;
    int l = gid & 63;
    unsigned int u = xr[(size_t)n * 64 + l];      // self term (2 bf16)
    float ax = __uint_as_float(u << 16);
    float ay = __uint_as_float(u & 0xffff0000u);
    int j = offs[n], je = offs[n + 1];
    for (; j + 3 < je; j += 4) {
        int a0 = bucket[j], a1 = bucket[j + 1], a2 = bucket[j + 2], a3 = bucket[j + 3];
        unsigned int u0 = xr[(size_t)a0 * 64 + l];
        unsigned int u1 = xr[(size_t)a1 * 64 + l];
        unsigned int u2 = xr[(size_t)a2 * 64 + l];
        unsigned int u3 = xr[(size_t)a3 * 64 + l];
        ax += __uint_as_float(u0 << 16) + __uint_as_float(u1 << 16)
            + __uint_as_float(u2 << 16) + __uint_as_float(u3 << 16);
        ay += __uint_as_float(u0 & 0xffff0000u) + __uint_as_float(u1 & 0xffff0000u)
            + __uint_as_float(u2 & 0xffff0000u) + __uint_as_float(u3 & 0xffff0000u);
    }
    for (; j < je; ++j) {
        unsigned int uu = xr[(size_t)bucket[j] * 64 + l];
        ax += __uint_as_float(uu << 16);
        ay += __uint_as_float(uu & 0xffff0000u);
    }
    hb[(size_t)n * 64 + l] = (unsigned)f2bf(ax) | ((unsigned)f2bf(ay) << 16);
}

// ---------------- fused MLP: out = relu(h@W1+b1)@W2 + b2 (h is bf16) ----------
__global__ __launch_bounds__(256, 2) void k_mlp(const unsigned short* __restrict__ hb,
                                                const unsigned short* __restrict__ w1t,
                                                const unsigned short* __restrict__ w2t,
                                                const float* __restrict__ b1,
                                                const float* __restrict__ b2,
                                                float* __restrict__ out) {
    __shared__ unsigned short lds[DD * DD];  // 32 KB, swizzled h tile
    const int t  = threadIdx.x;
    const int w  = t >> 6, l = t & 63;
    const int wr = w >> 1, wc = w & 1;
    const int hi = l >> 4, lo = l & 15;
    const long base_row = (long)blockIdx.x * 128;

    // stage bf16 h -> LDS (16B chunks, swizzled; no conversion needed)
    const uint4* hrow = reinterpret_cast<const uint4*>(hb);   // 16 chunks per row
#pragma unroll
    for (int it = 0; it < 8; ++it) {
        int idx = it * 256 + t;                 // 0..2047 chunk within tile
        int row = idx >> 4;
        long g = base_row + row;
        uint4 v = make_uint4(0u, 0u, 0u, 0u);
        if (g < NN) v = hrow[base_row * 16 + idx];
        int byte = (row * 256 + (idx & 15) * 16) ^ ((row & 7) << 4);
        *reinterpret_cast<uint4*>(reinterpret_cast<char*>(lds) + byte) = v;
    }
    __syncthreads();

    const f32x4 zero = {0.f, 0.f, 0.f, 0.f};

    // ---- GEMM1 ----
    bf16x8 bw1[4][4];
#pragma unroll
    for (int n = 0; n < 4; ++n)
#pragma unroll
        for (int k = 0; k < 4; ++k)
            bw1[n][k] = *reinterpret_cast<const bf16x8*>(
                w1t + (wc * 64 + n * 16 + lo) * DD + k * 32 + hi * 8);

    f32x4 acc[4][4];
#pragma unroll
    for (int m = 0; m < 4; ++m)
#pragma unroll
        for (int n = 0; n < 4; ++n) acc[m][n] = zero;
#pragma unroll
    for (int m = 0; m < 4; ++m) {
        bf16x8 a[4];
        int r = wr * 64 + m * 16 + lo;
#pragma unroll
        for (int k = 0; k < 4; ++k) {
            int byte = (r * 256 + k * 64 + hi * 16) ^ ((r & 7) << 4);
            a[k] = *reinterpret_cast<const bf16x8*>(reinterpret_cast<const char*>(lds) + byte);
        }
#pragma unroll
        for (int n = 0; n < 4; ++n)
#pragma unroll
            for (int k = 0; k < 4; ++k)
                acc[m][n] = __builtin_amdgcn_mfma_f32_16x16x32_bf16(a[k], bw1[n][k], acc[m][n], 0, 0, 0);
    }
    __syncthreads();

    // ---- epilogue 1: h1 = relu(acc+b1) -> LDS (swizzled) ----
    float bias1[4];
#pragma unroll
    for (int n = 0; n < 4; ++n) bias1[n] = b1[wc * 64 + n * 16 + lo];
#pragma unroll
    for (int m = 0; m < 4; ++m)
#pragma unroll
        for (int n = 0; n < 4; ++n)
#pragma unroll
            for (int g = 0; g < 4; ++g) {
                int row = wr * 64 + m * 16 + hi * 4 + g;   // D: col=lane&15, row=(lane>>4)*4+reg
                int col = wc * 64 + n * 16 + lo;
                float v = fmaxf(acc[m][n][g] + bias1[n], 0.f);
                int byte = (row * 256 + col * 2) ^ ((row & 7) << 4);
                *reinterpret_cast<unsigned short*>(reinterpret_cast<char*>(lds) + byte) = f2bf(v);
            }
    __syncthreads();

    // ---- GEMM2 ----
    bf16x8 bw2[4][4];
#pragma unroll
    for (int n = 0; n < 4; ++n)
#pragma unroll
        for (int k = 0; k < 4; ++k)
            bw2[n][k] = *reinterpret_cast<const bf16x8*>(
                w2t + (wc * 64 + n * 16 + lo) * DD + k * 32 + hi * 8);

    f32x4 acc2[4][4];
#pragma unroll
    for (int m = 0; m < 4; ++m)
#pragma unroll
        for (int n = 0; n < 4; ++n) acc2[m][n] = zero;
#pragma unroll
    for (int m = 0; m < 4; ++m) {
        bf16x8 a[4];
        int r = wr * 64 + m * 16 + lo;
#pragma unroll
        for (int k = 0; k < 4; ++k) {
            int byte = (r * 256 + k * 64 + hi * 16) ^ ((r & 7) << 4);
            a[k] = *reinterpret_cast<const bf16x8*>(reinterpret_cast<const char*>(lds) + byte);
        }
#pragma unroll
        for (int n = 0; n < 4; ++n)
#pragma unroll
            for (int k = 0; k < 4; ++k)
                acc2[m][n] = __builtin_amdgcn_mfma_f32_16x16x32_bf16(a[k], bw2[n][k], acc2[m][n], 0, 0, 0);
    }

    // ---- store out = acc2 + b2 (f32) ----
    float bias2[4];
#pragma unroll
    for (int n = 0; n < 4; ++n) bias2[n] = b2[wc * 64 + n * 16 + lo];
#pragma unroll
    for (int m = 0; m < 4; ++m)
#pragma unroll
        for (int n = 0; n < 4; ++n)
#pragma unroll
            for (int g = 0; g < 4; ++g) {
                long row = base_row + wr * 64 + m * 16 + hi * 4 + g;
                if (row < NN)
                    out[row * DD + wc * 64 + n * 16 + lo] = acc2[m][n][g] + bias2[n];
            }
}

extern "C" void kernel_launch(void* const* d_in, const int* in_sizes, int n_in,
                              void* d_out, int out_size, void* d_ws, size_t ws_size,
                              hipStream_t stream) {
    const float* x  = (const float*)d_in[0];
    const int*   ei = (const int*)d_in[1];
    const float* W1 = (const float*)d_in[2];
    const float* b1 = (const float*)d_in[3];
    const float* W2 = (const float*)d_in[4];
    const float* b2 = (const float*)d_in[5];
    float* out = (float*)d_out;

    char* ws = (char*)d_ws;
    unsigned short* xb  = (unsigned short*)ws;                 // 25,600,000 B
    unsigned short* w1t = (unsigned short*)(ws + 25600000);    // 32 KB
    unsigned short* w2t = w1t + DD * DD;                       // 32 KB
    unsigned short* hb  = (unsigned short*)(ws + 25665536);    // 25,600,000 B
    int* deg    = (int*)(ws + 51265536);                       // NN ints
    int* offs   = deg + NN;                                    // NN+1 ints (+pad)
    int* bucket = offs + NN + 4;                               // EE ints

    k_setup<<<CVT_BLKS + PREP_BLKS + ZERO_BLKS, 256, 0, stream>>>(x, W1, W2, xb, w1t, w2t, deg);
    k_hist<<<(EE + 255) / 256, 256, 0, stream>>>(ei, deg);
    k_scan<<<1, 1024, 0, stream>>>(deg, offs);
    k_fill<<<(EE + 255) / 256, 256, 0, stream>>>(ei, deg, offs, bucket);
    k_gather<<<(NN * 64 + 255) / 256, 256, 0, stream>>>(
        (const unsigned int*)xb, offs, bucket, (unsigned int*)hb);
    k_mlp<<<(NN + 127) / 128, 256, 0, stream>>>(hb, w1t, w2t, b1, b2, out);
}

// Round 10
// 253.494 us; speedup vs baseline: 1.2757x; 1.2362x over previous
//
#include <hip/hip_runtime.h>

#define NN 100000
#define EE 640000
#define DD 128

// k_setup block ranges
#define CVT_BLKS  12500   // 12500*256*4 = 12,800,000 = NN*DD exactly
#define PREP_BLKS 128     // 2*128*128 / 256
#define ZERO_BLKS 98      // ceil(25001 int4 / 256)

typedef short bf16x8 __attribute__((ext_vector_type(8)));
typedef float f32x4 __attribute__((ext_vector_type(4)));

__device__ __forceinline__ unsigned short f2bf(float f) {
    union { float f; unsigned int u; } a; a.f = f;
    unsigned int u = a.u + 0x7fffu + ((a.u >> 16) & 1u);   // RNE
    return (unsigned short)(u >> 16);
}

__device__ __forceinline__ int wave_incl_scan(int v, int lane) {
#pragma unroll
    for (int d = 1; d < 64; d <<= 1) {
        int u = __shfl_up(v, d, 64);
        if (lane >= d) v += u;
    }
    return v;
}

// ------------- setup: x->bf16, W->bf16 transposed, cnt=0 (one kernel) ----------
__global__ __launch_bounds__(256) void k_setup(const float* __restrict__ x,
                                               const float* __restrict__ W1,
                                               const float* __restrict__ W2,
                                               unsigned short* __restrict__ xb,
                                               unsigned short* __restrict__ w1t,
                                               unsigned short* __restrict__ w2t,
                                               int* __restrict__ cnt) {
    int b = blockIdx.x, t = threadIdx.x;
    if (b < CVT_BLKS) {
        int i = (b * 256 + t) * 4;
        float4 v = *reinterpret_cast<const float4*>(x + i);
        unsigned int u0 = (unsigned)f2bf(v.x) | ((unsigned)f2bf(v.y) << 16);
        unsigned int u1 = (unsigned)f2bf(v.z) | ((unsigned)f2bf(v.w) << 16);
        *reinterpret_cast<uint2*>(xb + i) = make_uint2(u0, u1);
    } else if (b < CVT_BLKS + PREP_BLKS) {
        int idx = (b - CVT_BLKS) * 256 + t;            // 0 .. 32767
        const float* W = (idx < DD * DD) ? W1 : W2;
        unsigned short* O = (idx < DD * DD) ? w1t : w2t;
        int i = idx & (DD * DD - 1);
        int n = i >> 7, k = i & (DD - 1);
        O[i] = f2bf(W[k * DD + n]);                    // O[n*128+k] = W[k][n]
    } else {
        int idx = (b - CVT_BLKS - PREP_BLKS) * 256 + t;
        if (idx < 25001)                               // cnt[0..NN+3], incl gcount
            reinterpret_cast<int4*>(cnt)[idx] = make_int4(0, 0, 0, 0);
    }
}

// ---------------- CSR build ----------------------------------------------------
__global__ __launch_bounds__(256) void k_hist(const int* __restrict__ ei,
                                              int* __restrict__ cnt) {
    int e = blockIdx.x * 256 + threadIdx.x;
    if (e >= EE) return;
    atomicAdd(&cnt[ei[EE + e]], 1);
}

// range allocator: offs[n] = start of node n's bucket range; cnt[n] reset to
// start (fill cursor). Ranges disjoint but NOT in node order (sum order free).
// One atomicAdd on gcount per 256-node block (391 total).
__global__ __launch_bounds__(256) void k_offs(int* __restrict__ cnt,
                                              int* __restrict__ offs,
                                              int* __restrict__ gcount) {
    int t = threadIdx.x, lane = t & 63, w = t >> 6;
    int i = blockIdx.x * 256 + t;
    int v = (i < NN) ? cnt[i] : 0;
    int s = wave_incl_scan(v, lane);          // inclusive within wave
    __shared__ int wsum[4];
    __shared__ int base;
    if (lane == 63) wsum[w] = s;
    __syncthreads();
    if (t == 0)
        base = atomicAdd(gcount, wsum[0] + wsum[1] + wsum[2] + wsum[3]);
    __syncthreads();
    int off = base;
    for (int k = 0; k < w; ++k) off += wsum[k];
    int start = off + s - v;                  // exclusive within block + base
    if (i < NN) { offs[i] = start; cnt[i] = start; }
}

__global__ __launch_bounds__(256) void k_fill(const int* __restrict__ ei,
                                              int* __restrict__ cnt,
                                              int* __restrict__ bucket) {
    int e = blockIdx.x * 256 + threadIdx.x;
    if (e >= EE) return;
    int r = ei[e];
    int c = ei[EE + e];
    int p = atomicAdd(&cnt[c], 1);            // absolute slot; after fill cnt[c]=end
    bucket[p] = r;
}

// -------- gather: hb[n] = bf16( x[n] + sum_{src->n} x[src] ), one node/wave ----
// range = [offs[n], cnt[n])  (cnt[n] == end after k_fill)
__global__ __launch_bounds__(256) void k_gather(const unsigned int* __restrict__ xr,
                                                const int* __restrict__ offs,
                                                const int* __restrict__ cnt,
                                                const int* __restrict__ bucket,
                                                unsigned int* __restrict__ hb) {
    int gid = blockIdx.x * 256 + threadIdx.x;
    int n = gid >> 6;
    if (n >= NN) return;
    int l = gid & 63;
    unsigned int u = xr[(size_t)n * 64 + l];      // self term (2 bf16)
    float ax = __uint_as_float(u << 16);
    float ay = __uint_as_float(u & 0xffff0000u);
    int j = offs[n], je = cnt[n];
    for (; j + 7 < je; j += 8) {
        int a0 = bucket[j],     a1 = bucket[j + 1], a2 = bucket[j + 2], a3 = bucket[j + 3];
        int a4 = bucket[j + 4], a5 = bucket[j + 5], a6 = bucket[j + 6], a7 = bucket[j + 7];
        unsigned int u0 = xr[(size_t)a0 * 64 + l];
        unsigned int u1 = xr[(size_t)a1 * 64 + l];
        unsigned int u2 = xr[(size_t)a2 * 64 + l];
        unsigned int u3 = xr[(size_t)a3 * 64 + l];
        unsigned int u4 = xr[(size_t)a4 * 64 + l];
        unsigned int u5 = xr[(size_t)a5 * 64 + l];
        unsigned int u6 = xr[(size_t)a6 * 64 + l];
        unsigned int u7 = xr[(size_t)a7 * 64 + l];
        ax += __uint_as_float(u0 << 16) + __uint_as_float(u1 << 16)
            + __uint_as_float(u2 << 16) + __uint_as_float(u3 << 16)
            + __uint_as_float(u4 << 16) + __uint_as_float(u5 << 16)
            + __uint_as_float(u6 << 16) + __uint_as_float(u7 << 16);
        ay += __uint_as_float(u0 & 0xffff0000u) + __uint_as_float(u1 & 0xffff0000u)
            + __uint_as_float(u2 & 0xffff0000u) + __uint_as_float(u3 & 0xffff0000u)
            + __uint_as_float(u4 & 0xffff0000u) + __uint_as_float(u5 & 0xffff0000u)
            + __uint_as_float(u6 & 0xffff0000u) + __uint_as_float(u7 & 0xffff0000u);
    }
    if (j + 3 < je) {
        int a0 = bucket[j], a1 = bucket[j + 1], a2 = bucket[j + 2], a3 = bucket[j + 3];
        unsigned int u0 = xr[(size_t)a0 * 64 + l];
        unsigned int u1 = xr[(size_t)a1 * 64 + l];
        unsigned int u2 = xr[(size_t)a2 * 64 + l];
        unsigned int u3 = xr[(size_t)a3 * 64 + l];
        ax += __uint_as_float(u0 << 16) + __uint_as_float(u1 << 16)
            + __uint_as_float(u2 << 16) + __uint_as_float(u3 << 16);
        ay += __uint_as_float(u0 & 0xffff0000u) + __uint_as_float(u1 & 0xffff0000u)
            + __uint_as_float(u2 & 0xffff0000u) + __uint_as_float(u3 & 0xffff0000u);
        j += 4;
    }
    for (; j < je; ++j) {
        unsigned int uu = xr[(size_t)bucket[j] * 64 + l];
        ax += __uint_as_float(uu << 16);
        ay += __uint_as_float(uu & 0xffff0000u);
    }
    hb[(size_t)n * 64 + l] = (unsigned)f2bf(ax) | ((unsigned)f2bf(ay) << 16);
}

// ---------------- fused MLP: out = relu(h@W1+b1)@W2 + b2 (h is bf16) ----------
__global__ __launch_bounds__(256, 2) void k_mlp(const unsigned short* __restrict__ hb,
                                                const unsigned short* __restrict__ w1t,
                                                const unsigned short* __restrict__ w2t,
                                                const float* __restrict__ b1,
                                                const float* __restrict__ b2,
                                                float* __restrict__ out) {
    __shared__ unsigned short lds[DD * DD];  // 32 KB, swizzled h tile
    const int t  = threadIdx.x;
    const int w  = t >> 6, l = t & 63;
    const int wr = w >> 1, wc = w & 1;
    const int hi = l >> 4, lo = l & 15;
    const long base_row = (long)blockIdx.x * 128;

    // stage bf16 h -> LDS (16B chunks, swizzled; no conversion needed)
    const uint4* hrow = reinterpret_cast<const uint4*>(hb);   // 16 chunks per row
#pragma unroll
    for (int it = 0; it < 8; ++it) {
        int idx = it * 256 + t;                 // 0..2047 chunk within tile
        int row = idx >> 4;
        long g = base_row + row;
        uint4 v = make_uint4(0u, 0u, 0u, 0u);
        if (g < NN) v = hrow[base_row * 16 + idx];
        int byte = (row * 256 + (idx & 15) * 16) ^ ((row & 7) << 4);
        *reinterpret_cast<uint4*>(reinterpret_cast<char*>(lds) + byte) = v;
    }
    __syncthreads();

    const f32x4 zero = {0.f, 0.f, 0.f, 0.f};

    // ---- GEMM1 ----
    bf16x8 bw1[4][4];
#pragma unroll
    for (int n = 0; n < 4; ++n)
#pragma unroll
        for (int k = 0; k < 4; ++k)
            bw1[n][k] = *reinterpret_cast<const bf16x8*>(
                w1t + (wc * 64 + n * 16 + lo) * DD + k * 32 + hi * 8);

    f32x4 acc[4][4];
#pragma unroll
    for (int m = 0; m < 4; ++m)
#pragma unroll
        for (int n = 0; n < 4; ++n) acc[m][n] = zero;
#pragma unroll
    for (int m = 0; m < 4; ++m) {
        bf16x8 a[4];
        int r = wr * 64 + m * 16 + lo;
#pragma unroll
        for (int k = 0; k < 4; ++k) {
            int byte = (r * 256 + k * 64 + hi * 16) ^ ((r & 7) << 4);
            a[k] = *reinterpret_cast<const bf16x8*>(reinterpret_cast<const char*>(lds) + byte);
        }
#pragma unroll
        for (int n = 0; n < 4; ++n)
#pragma unroll
            for (int k = 0; k < 4; ++k)
                acc[m][n] = __builtin_amdgcn_mfma_f32_16x16x32_bf16(a[k], bw1[n][k], acc[m][n], 0, 0, 0);
    }
    __syncthreads();

    // ---- epilogue 1: h1 = relu(acc+b1) -> LDS (swizzled) ----
    float bias1[4];
#pragma unroll
    for (int n = 0; n < 4; ++n) bias1[n] = b1[wc * 64 + n * 16 + lo];
#pragma unroll
    for (int m = 0; m < 4; ++m)
#pragma unroll
        for (int n = 0; n < 4; ++n)
#pragma unroll
            for (int g = 0; g < 4; ++g) {
                int row = wr * 64 + m * 16 + hi * 4 + g;   // D: col=lane&15, row=(lane>>4)*4+reg
                int col = wc * 64 + n * 16 + lo;
                float v = fmaxf(acc[m][n][g] + bias1[n], 0.f);
                int byte = (row * 256 + col * 2) ^ ((row & 7) << 4);
                *reinterpret_cast<unsigned short*>(reinterpret_cast<char*>(lds) + byte) = f2bf(v);
            }
    __syncthreads();

    // ---- GEMM2 ----
    bf16x8 bw2[4][4];
#pragma unroll
    for (int n = 0; n < 4; ++n)
#pragma unroll
        for (int k = 0; k < 4; ++k)
            bw2[n][k] = *reinterpret_cast<const bf16x8*>(
                w2t + (wc * 64 + n * 16 + lo) * DD + k * 32 + hi * 8);

    f32x4 acc2[4][4];
#pragma unroll
    for (int m = 0; m < 4; ++m)
#pragma unroll
        for (int n = 0; n < 4; ++n) acc2[m][n] = zero;
#pragma unroll
    for (int m = 0; m < 4; ++m) {
        bf16x8 a[4];
        int r = wr * 64 + m * 16 + lo;
#pragma unroll
        for (int k = 0; k < 4; ++k) {
            int byte = (r * 256 + k * 64 + hi * 16) ^ ((r & 7) << 4);
            a[k] = *reinterpret_cast<const bf16x8*>(reinterpret_cast<const char*>(lds) + byte);
        }
#pragma unroll
        for (int n = 0; n < 4; ++n)
#pragma unroll
            for (int k = 0; k < 4; ++k)
                acc2[m][n] = __builtin_amdgcn_mfma_f32_16x16x32_bf16(a[k], bw2[n][k], acc2[m][n], 0, 0, 0);
    }

    // ---- store out = acc2 + b2 (f32) ----
    float bias2[4];
#pragma unroll
    for (int n = 0; n < 4; ++n) bias2[n] = b2[wc * 64 + n * 16 + lo];
#pragma unroll
    for (int m = 0; m < 4; ++m)
#pragma unroll
        for (int n = 0; n < 4; ++n)
#pragma unroll
            for (int g = 0; g < 4; ++g) {
                long row = base_row + wr * 64 + m * 16 + hi * 4 + g;
                if (row < NN)
                    out[row * DD + wc * 64 + n * 16 + lo] = acc2[m][n][g] + bias2[n];
            }
}

extern "C" void kernel_launch(void* const* d_in, const int* in_sizes, int n_in,
                              void* d_out, int out_size, void* d_ws, size_t ws_size,
                              hipStream_t stream) {
    const float* x  = (const float*)d_in[0];
    const int*   ei = (const int*)d_in[1];
    const float* W1 = (const float*)d_in[2];
    const float* b1 = (const float*)d_in[3];
    const float* W2 = (const float*)d_in[4];
    const float* b2 = (const float*)d_in[5];
    float* out = (float*)d_out;

    char* ws = (char*)d_ws;
    unsigned short* xb  = (unsigned short*)ws;                 // 25,600,000 B
    unsigned short* w1t = (unsigned short*)(ws + 25600000);    // 32 KB
    unsigned short* w2t = w1t + DD * DD;                       // 32 KB
    unsigned short* hb  = (unsigned short*)(ws + 25665536);    // 25,600,000 B
    int* cnt    = (int*)(ws + 51265536);                       // NN+4 ints (cnt[NN]=gcount)
    int* offs   = cnt + NN + 4;                                // NN ints
    int* bucket = offs + NN + 4;                               // EE ints

    k_setup<<<CVT_BLKS + PREP_BLKS + ZERO_BLKS, 256, 0, stream>>>(x, W1, W2, xb, w1t, w2t, cnt);
    k_hist<<<(EE + 255) / 256, 256, 0, stream>>>(ei, cnt);
    k_offs<<<(NN + 255) / 256, 256, 0, stream>>>(cnt, offs, cnt + NN);
    k_fill<<<(EE + 255) / 256, 256, 0, stream>>>(ei, cnt, bucket);
    k_gather<<<(NN * 64 + 255) / 256, 256, 0, stream>>>(
        (const unsigned int*)xb, offs, cnt, bucket, (unsigned int*)hb);
    k_mlp<<<(NN + 127) / 128, 256, 0, stream>>>(hb, w1t, w2t, b1, b2, out);
}